// Round 5
// baseline (1194.647 us; speedup 1.0000x reference)
//
#include <hip/hip_runtime.h>
#include <hip/hip_bf16.h>

// Problem constants
// B=32, L=128, C=20, TOKEN_EMBED=300, CHAR_EMBED=50, NUM_FILTERS=200, KERNEL=3
// HID=256, LABELS=8, NS=6, D0=500 (padded 512), D1=512, BL=4096

typedef float floatx2 __attribute__((ext_vector_type(2)));
typedef short bf16x8 __attribute__((ext_vector_type(8)));
typedef float f32x4  __attribute__((ext_vector_type(4)));

__device__ __forceinline__ unsigned short f2bf(float x) {
    unsigned u = __float_as_uint(x);
    unsigned r = (u + 0x7fffu + ((u >> 16) & 1u)) >> 16;
    return (unsigned short)r;
}

// packed fp32 FMA with op_sel broadcast of h (low or high half of the pair)
__device__ __forceinline__ void pk_fma_bl(floatx2& acc, floatx2 w, floatx2 h) {
    asm("v_pk_fma_f32 %0, %1, %2, %0 op_sel_hi:[1,0,1]" : "+v"(acc) : "v"(w), "v"(h));
}
__device__ __forceinline__ void pk_fma_bh(floatx2& acc, floatx2 w, floatx2 h) {
    asm("v_pk_fma_f32 %0, %1, %2, %0 op_sel:[0,1,0]" : "+v"(acc) : "v"(w), "v"(h));
}

__device__ __forceinline__ float fsig(float x) {
    return __builtin_amdgcn_rcpf(1.f + __expf(-x));
}
__device__ __forceinline__ float ftanh(float x) {
    return fmaf(-2.f, __builtin_amdgcn_rcpf(1.f + __expf(2.f * x)), 1.f);
}

// 4 k-values (one uint4 of packed fp8 gate weights) x 4 gates = 16 MACs
__device__ __forceinline__ void dot4(floatx2& aif0, floatx2& ago0,
                                     floatx2& aif1, floatx2& ago1,
                                     uint4 w, const float* hsp, int k4) {
    float4 hv = *(const float4*)(hsp + k4 * 4);   // broadcast (same addr all lanes)
    floatx2 h01; h01.x = hv.x; h01.y = hv.y;
    floatx2 h23; h23.x = hv.z; h23.y = hv.w;
    floatx2 lo, hi;
    lo = __builtin_amdgcn_cvt_pk_f32_fp8((int)w.x, false);
    hi = __builtin_amdgcn_cvt_pk_f32_fp8((int)w.x, true);
    pk_fma_bl(aif0, lo, h01); pk_fma_bl(ago0, hi, h01);
    lo = __builtin_amdgcn_cvt_pk_f32_fp8((int)w.y, false);
    hi = __builtin_amdgcn_cvt_pk_f32_fp8((int)w.y, true);
    pk_fma_bh(aif0, lo, h01); pk_fma_bh(ago0, hi, h01);
    lo = __builtin_amdgcn_cvt_pk_f32_fp8((int)w.z, false);
    hi = __builtin_amdgcn_cvt_pk_f32_fp8((int)w.z, true);
    pk_fma_bl(aif1, lo, h23); pk_fma_bl(ago1, hi, h23);
    lo = __builtin_amdgcn_cvt_pk_f32_fp8((int)w.w, false);
    hi = __builtin_amdgcn_cvt_pk_f32_fp8((int)w.w, true);
    pk_fma_bh(aif1, lo, h23); pk_fma_bh(ago1, hi, h23);
}

// ---------------------------------------------------------------------------
// prep_all: merged prep.
//  blocks [0, 8566): elementwise misc (coalesced):
//   - wih0 (2048x500 fp32) -> wbf0 (2048x512 bf16, zero-padded)
//   - wih1 (2048x512 fp32) -> wbf1 (2048x512 bf16)
//   - crf_w -> crfbf (128x512 bf16, rows 48..127 zero)  [row jj = kL*6+n]
//   - conv_w transpose -> convWT ; outp zero
//  blocks [8566, 8630): w_hh tile-transpose pack -> fp8 uint4 per (dir,k4,t)
//   (byte-identical to the verified strided prep layout)
// ---------------------------------------------------------------------------
#define MISC_BLOCKS 8566
__global__ __launch_bounds__(256) void prep_all(
    const float* __restrict__ wih0, const float* __restrict__ wih1,
    const float* __restrict__ crf_w, const float* __restrict__ conv_w,
    const float* __restrict__ wh0, const float* __restrict__ wh1,
    unsigned short* __restrict__ wbf0, unsigned short* __restrict__ wbf1,
    unsigned short* __restrict__ crfbf, float* __restrict__ convWT,
    uint4* __restrict__ Wp0, uint4* __restrict__ Wp1,
    float* __restrict__ outp)
{
    __shared__ float sxw[4][64][65];
    const int tid = threadIdx.x;
    if (blockIdx.x >= MISC_BLOCKS) {
        const int bid   = blockIdx.x - MISC_BLOCKS;
        const int layer = bid >> 5;
        const int dir   = (bid >> 4) & 1;
        const int tt    = (bid >> 2) & 3;
        const int ktile = bid & 3;
        const float* w = (layer ? wh1 : wh0) + dir * 1024 * 256;
        uint4* dst = layer ? Wp1 : Wp0;
        const int t0 = tt * 64, k0 = ktile * 64;
        #pragma unroll
        for (int g = 0; g < 4; ++g)
            #pragma unroll
            for (int q = 0; q < 4; ++q) {
                int lin = q * 256 + tid;
                int tr = lin >> 4, kc = (lin & 15) * 4;
                float4 v = *(const float4*)&w[(g * 256 + t0 + tr) * 256 + k0 + kc];
                sxw[g][tr][kc + 0] = v.x; sxw[g][tr][kc + 1] = v.y;
                sxw[g][tr][kc + 2] = v.z; sxw[g][tr][kc + 3] = v.w;
            }
        __syncthreads();
        const int t = tid & 63, k4g = tid >> 6;
        #pragma unroll
        for (int q = 0; q < 4; ++q) {
            int k4l = k4g * 4 + q;           // 0..15
            unsigned wrd[4];
            #pragma unroll
            for (int j = 0; j < 4; ++j) {
                int kc = k4l * 4 + j;
                float wi = sxw[0][t][kc], wf = sxw[1][t][kc];
                float wg = sxw[2][t][kc], wo = sxw[3][t][kc];
                int u = __builtin_amdgcn_cvt_pk_fp8_f32(wi, wf, 0, false);
                u     = __builtin_amdgcn_cvt_pk_fp8_f32(wg, wo, u, true);
                wrd[j] = (unsigned)u;
            }
            int k4 = (k0 >> 2) + k4l;
            dst[((size_t)dir * 64 + k4) * 256 + (t0 + t)] =
                make_uint4(wrd[0], wrd[1], wrd[2], wrd[3]);
        }
        return;
    }
    int idx = blockIdx.x * 256 + tid;
    if (idx == 0) outp[0] = 0.f;
    const int NW = 2048 * 512;
    if (idx < NW) {
        int n = idx >> 9, k = idx & 511;
        wbf0[idx] = (k < 500) ? f2bf(wih0[n * 500 + k]) : (unsigned short)0;
        return;
    }
    idx -= NW;
    if (idx < NW) {
        wbf1[idx] = f2bf(wih1[idx]);
        return;
    }
    idx -= NW;
    if (idx < 128 * 512) {
        int jj = idx >> 9, d = idx & 511;
        unsigned short v = 0;
        if (jj < 48) {
            int kL = jj / 6, n = jj % 6;
            v = f2bf(crf_w[(kL * 512 + d) * 6 + n]);
        }
        crfbf[idx] = v;
        return;
    }
    idx -= 128 * 512;
    if (idx < 30000) {
        int f = idx % 200, ek = idx / 200;
        int e = ek / 3, kk = ek % 3;
        convWT[idx] = conv_w[(f * 50 + e) * 3 + kk];
        return;
    }
}

// ---------------------------------------------------------------------------
// Embeddings + char conv + concat -> inp (4096 x 512 bf16, cols 500..511 = 0)
// 512 threads: conv e-loop split in half (eh=tid>>8), partials combined in LDS.
// ---------------------------------------------------------------------------
__global__ __launch_bounds__(512) void embed_conv(
    const int* __restrict__ iv, const int* __restrict__ ov, const int* __restrict__ ch,
    const float* __restrict__ emb, const float* __restrict__ ooev, const float* __restrict__ ctab,
    const float* __restrict__ convWT, const float* __restrict__ convB,
    unsigned short* __restrict__ inp)
{
    const int bl = blockIdx.x;
    const int tid = threadIdx.x;
    __shared__ float sx[50 * 20];
    __shared__ float pc[200][22];
    const int ivv = iv[bl];
    const int ovv = ov[bl];
    const float mo = (ovv != 0) ? 1.f : 0.f;
    if (tid < 300)
        inp[bl * 512 + tid] = f2bf(emb[(size_t)ivv * 300 + tid] + mo * ooev[(size_t)ovv * 300 + tid]);
    if (tid >= 500) inp[bl * 512 + tid] = 0;    // pad cols 500..511
    for (int i = tid; i < 1000; i += 512) {
        int cI = i / 50, e = i % 50;
        int id = ch[bl * 20 + cI];
        sx[e * 20 + cI] = id ? ctab[id * 50 + e] : 0.f;
    }
    __syncthreads();
    const int f = tid & 255, eh = tid >> 8;
    float acc[22];
    if (f < 200) {
        float init = eh ? 0.f : convB[f];
        #pragma unroll
        for (int o = 0; o < 22; ++o) acc[o] = init;
        const int e0 = eh * 25;
        for (int e = e0; e < e0 + 25; ++e) {
            float xr[20];
            #pragma unroll
            for (int q = 0; q < 5; ++q) {
                float4 v = *(const float4*)&sx[e * 20 + q * 4];
                xr[q * 4 + 0] = v.x; xr[q * 4 + 1] = v.y;
                xr[q * 4 + 2] = v.z; xr[q * 4 + 3] = v.w;
            }
            float w0 = convWT[(e * 3 + 0) * 200 + f];
            float w1 = convWT[(e * 3 + 1) * 200 + f];
            float w2 = convWT[(e * 3 + 2) * 200 + f];
            #pragma unroll
            for (int o = 0; o < 22; ++o) {
                float s = acc[o];
                if (o >= 2)            s = fmaf(xr[o - 2], w0, s);
                if (o >= 1 && o <= 20) s = fmaf(xr[o - 1], w1, s);
                if (o <= 19)           s = fmaf(xr[o],     w2, s);
                acc[o] = s;
            }
        }
        if (eh) {
            #pragma unroll
            for (int o = 0; o < 22; ++o) pc[f][o] = acc[o];
        }
    }
    __syncthreads();
    if (f < 200 && eh == 0) {
        float mx = acc[0] + pc[f][0];
        #pragma unroll
        for (int o = 1; o < 22; ++o) mx = fmaxf(mx, acc[o] + pc[f][o]);
        inp[bl * 512 + 300 + f] = f2bf(1.f / (1.f + expf(-mx)));
    }
}

// ---------------------------------------------------------------------------
// Pure-bf16 MFMA GEMM: A (Mx512 bf16), B (rows of 512 bf16 = output cols),
// K=512 exact. ldC = C row stride; Nguard = #valid output cols (writes
// guarded). Used for both main GEMMs (ldC=Nguard=2048) and the emission
// GEMM (B = crfbf 128x512 zero-padded, ldC=Nguard=48).
// ---------------------------------------------------------------------------
__global__ __launch_bounds__(256) void gemm_bf16(
    const unsigned short* __restrict__ A, const unsigned short* __restrict__ Bm,
    const float* __restrict__ bias, float* __restrict__ C, int ldC, int Nguard)
{
    __shared__ unsigned short As[4][128][8];
    __shared__ unsigned short Bs[4][128][8];
    const int tid  = threadIdx.x;
    const int wave = tid >> 6, lane = tid & 63;
    const int quad = lane >> 4, lr = lane & 15;
    const int m0 = blockIdx.y * 128, n0 = blockIdx.x * 128;

    f32x4 acc[2][8];
    #pragma unroll
    for (int mt = 0; mt < 2; ++mt)
        #pragma unroll
        for (int nt = 0; nt < 8; ++nt) acc[mt][nt] = (f32x4){0.f, 0.f, 0.f, 0.f};

    for (int kt = 0; kt < 16; ++kt) {
        #pragma unroll
        for (int p = 0; p < 2; ++p) {
            int lin = p * 256 + tid;
            int row = lin & 127, c = lin >> 7;     // c in 0..3 over both passes
            *(bf16x8*)&As[c][row][0] =
                *(const bf16x8*)&A[(size_t)(m0 + row) * 512 + kt * 32 + c * 8];
            *(bf16x8*)&Bs[c][row][0] =
                *(const bf16x8*)&Bm[(size_t)(n0 + row) * 512 + kt * 32 + c * 8];
        }
        __syncthreads();
        bf16x8 bfr[8];
        #pragma unroll
        for (int nt = 0; nt < 8; ++nt)
            bfr[nt] = *(const bf16x8*)&Bs[quad][nt * 16 + lr][0];
        #pragma unroll
        for (int mt = 0; mt < 2; ++mt) {
            bf16x8 afr = *(const bf16x8*)&As[quad][wave * 32 + mt * 16 + lr][0];
            #pragma unroll
            for (int nt = 0; nt < 8; ++nt)
                acc[mt][nt] = __builtin_amdgcn_mfma_f32_16x16x32_bf16(
                    afr, bfr[nt], acc[mt][nt], 0, 0, 0);
        }
        __syncthreads();
    }
    #pragma unroll
    for (int mt = 0; mt < 2; ++mt)
        #pragma unroll
        for (int r = 0; r < 4; ++r) {
            int m = m0 + wave * 32 + mt * 16 + quad * 4 + r;
            #pragma unroll
            for (int nt = 0; nt < 8; ++nt) {
                int n = n0 + nt * 16 + lr;
                if (n < Nguard) C[(size_t)m * ldC + n] = acc[mt][nt][r] + bias[n];
            }
        }
}

// ---------------------------------------------------------------------------
// LSTM recurrence v13b (UNCHANGED): 1024 threads, 4-way k-split,
// 36 LDS groups + 28 L2-streamed groups, no register-resident weights.
// ---------------------------------------------------------------------------
#define L4LDS 36
__global__ __launch_bounds__(1024) void lstm_rec(
    const float* __restrict__ xs, const uint4* __restrict__ Wp,
    const float* __restrict__ mask, float* __restrict__ out,
    unsigned short* __restrict__ outb)
{
    const int tid = threadIdx.x;
    const int t   = tid & 255;
    const int kh  = tid >> 8;            // wave-uniform
    const int b   = blockIdx.x >> 1;
    const int dir = blockIdx.x & 1;
    __shared__ uint4 wlds[L4LDS * 256];          // 147456 B
    __shared__ float4 part[3 * 256];             // 12288 B
    __shared__ __align__(16) float hs[256];
    __shared__ float msk[128];

    const uint4* wp = Wp + (size_t)dir * 64 * 256;
    for (int j = tid; j < L4LDS * 256; j += 1024) wlds[j] = wp[j];
    if (tid < 256) hs[tid] = 0.f;
    if (tid < 128) msk[tid] = mask[b * 128 + tid];
    __syncthreads();

    const uint4* sp = wp + t;                    // streamed: sp[g*256]
    float h = 0.f, c = 0.f;                      // live on kh==0 (t-owners)
    for (int s = 0; s < 128; ++s) {
        const int l = dir ? (127 - s) : s;
        floatx2 aif0 = {0.f, 0.f}, ago0 = {0.f, 0.f};
        floatx2 aif1 = {0.f, 0.f}, ago1 = {0.f, 0.f};
        float gi, gf, gg2, go;
        if (kh == 0) {
            const float* gxp = xs + ((size_t)(b * 128 + l) * 2048 + dir * 1024 + t);
            gi = gxp[0]; gf = gxp[256]; gg2 = gxp[512]; go = gxp[768];
            #pragma unroll 4
            for (int k4 = 0; k4 < 13; ++k4)
                dot4(aif0, ago0, aif1, ago1, wlds[k4 * 256 + t], hs, k4);
        } else if (kh == 1) {
            uint4 a0 = sp[36 * 256], a1 = sp[37 * 256];
            uint4 a2 = sp[38 * 256], a3 = sp[39 * 256];
            #pragma unroll 4
            for (int k4 = 13; k4 < 27; ++k4)
                dot4(aif0, ago0, aif1, ago1, wlds[k4 * 256 + t], hs, k4);
            dot4(aif0, ago0, aif1, ago1, a0, hs, 36);
            dot4(aif0, ago0, aif1, ago1, a1, hs, 37);
            dot4(aif0, ago0, aif1, ago1, a2, hs, 38);
            dot4(aif0, ago0, aif1, ago1, a3, hs, 39);
        } else if (kh == 2) {
            uint4 a0 = sp[40 * 256], a1 = sp[41 * 256];
            uint4 a2 = sp[42 * 256], a3 = sp[43 * 256];
            uint4 b0 = sp[44 * 256], b1 = sp[45 * 256];
            uint4 b2 = sp[46 * 256], b3 = sp[47 * 256];
            #pragma unroll 3
            for (int k4 = 27; k4 < 36; ++k4)
                dot4(aif0, ago0, aif1, ago1, wlds[k4 * 256 + t], hs, k4);
            dot4(aif0, ago0, aif1, ago1, a0, hs, 40);
            dot4(aif0, ago0, aif1, ago1, a1, hs, 41);
            dot4(aif0, ago0, aif1, ago1, a2, hs, 42);
            dot4(aif0, ago0, aif1, ago1, a3, hs, 43);
            dot4(aif0, ago0, aif1, ago1, b0, hs, 44);
            dot4(aif0, ago0, aif1, ago1, b1, hs, 45);
            dot4(aif0, ago0, aif1, ago1, b2, hs, 46);
            dot4(aif0, ago0, aif1, ago1, b3, hs, 47);
        } else {
            uint4 a0 = sp[48 * 256], a1 = sp[49 * 256];
            uint4 a2 = sp[50 * 256], a3 = sp[51 * 256];
            uint4 b0 = sp[52 * 256], b1 = sp[53 * 256];
            uint4 b2 = sp[54 * 256], b3 = sp[55 * 256];
            dot4(aif0, ago0, aif1, ago1, a0, hs, 48);
            dot4(aif0, ago0, aif1, ago1, a1, hs, 49);
            dot4(aif0, ago0, aif1, ago1, a2, hs, 50);
            dot4(aif0, ago0, aif1, ago1, a3, hs, 51);
            a0 = sp[56 * 256]; a1 = sp[57 * 256];
            a2 = sp[58 * 256]; a3 = sp[59 * 256];
            dot4(aif0, ago0, aif1, ago1, b0, hs, 52);
            dot4(aif0, ago0, aif1, ago1, b1, hs, 53);
            dot4(aif0, ago0, aif1, ago1, b2, hs, 54);
            dot4(aif0, ago0, aif1, ago1, b3, hs, 55);
            b0 = sp[60 * 256]; b1 = sp[61 * 256];
            b2 = sp[62 * 256]; b3 = sp[63 * 256];
            dot4(aif0, ago0, aif1, ago1, a0, hs, 56);
            dot4(aif0, ago0, aif1, ago1, a1, hs, 57);
            dot4(aif0, ago0, aif1, ago1, a2, hs, 58);
            dot4(aif0, ago0, aif1, ago1, a3, hs, 59);
            dot4(aif0, ago0, aif1, ago1, b0, hs, 60);
            dot4(aif0, ago0, aif1, ago1, b1, hs, 61);
            dot4(aif0, ago0, aif1, ago1, b2, hs, 62);
            dot4(aif0, ago0, aif1, ago1, b3, hs, 63);
        }
        floatx2 aif = aif0 + aif1;
        floatx2 ago = ago0 + ago1;
        if (kh != 0)
            part[(kh - 1) * 256 + t] = make_float4(aif.x, aif.y, ago.x, ago.y);
        __syncthreads();                 // partials written; hs reads done
        if (kh == 0) {
            float4 p0 = part[t], p1 = part[256 + t], p2 = part[512 + t];
            float sai = aif.x + gi  + p0.x + p1.x + p2.x;
            float saf = aif.y + gf  + p0.y + p1.y + p2.y;
            float sag = ago.x + gg2 + p0.z + p1.z + p2.z;
            float sao = ago.y + go  + p0.w + p1.w + p2.w;
            float ig = fsig(sai);
            float fg = fsig(saf);
            float og = fsig(sao);
            float gg = ftanh(sag);
            float cn = fmaf(fg, c, ig * gg);
            float hn = og * ftanh(cn);
            float m = msk[l];
            h = m * hn + (1.f - m) * h;
            c = m * cn + (1.f - m) * c;
            hs[t] = h;
            size_t oi = (size_t)(b * 128 + l) * 512 + dir * 256 + t;
            out[oi]  = h;
            outb[oi] = f2bf(h);
        }
        __syncthreads();                 // new hs visible for next step
    }
}
#undef L4LDS

// ---------------------------------------------------------------------------
// CRF loss v2: 32 blocks = (label k x batch-quarter), 64 threads (1 wave,
// 48 active = 8 batches x 6 states). Single-wave lockstep -> NO barriers in
// the 127-step alpha recurrence (LDS ordering by program order + lgkmcnt).
// ---------------------------------------------------------------------------
__global__ __launch_bounds__(64) void crf_loss(
    const float* __restrict__ em, const float* __restrict__ trans,
    const int* __restrict__ target, const float* __restrict__ mask,
    float* __restrict__ outp)
{
    const int k  = blockIdx.x >> 2;
    const int bq = blockIdx.x & 3;
    const int tid = threadIdx.x;
    __shared__ float T[36];
    __shared__ float As[8][6];
    __shared__ float red[48];
    __shared__ float res[8];
    if (tid < 36) T[tid] = trans[k * 36 + tid];
    if (tid < 48) {
        const int bloc = tid / 6;
        const int j    = tid - bloc * 6;
        const int b    = bq * 8 + bloc;
        const int* tg = target + (k * 32 + b) * 128;
        float sc = 0.f;
        for (int l = j; l < 128; l += 6) {
            int y = tg[l];
            float m = mask[b * 128 + l];
            sc += m * em[(b * 128 + l) * 48 + k * 6 + y];
            if (l > 0) sc += m * T[tg[l - 1] * 6 + y];
        }
        red[tid] = sc;
        float a = em[(b * 128) * 48 + k * 6 + j];
        As[bloc][j] = a;
        for (int l = 1; l < 128; ++l) {
            float e = em[(b * 128 + l) * 48 + k * 6 + j];
            float v0 = As[bloc][0] + T[0 * 6 + j];
            float v1 = As[bloc][1] + T[1 * 6 + j];
            float v2 = As[bloc][2] + T[2 * 6 + j];
            float v3 = As[bloc][3] + T[3 * 6 + j];
            float v4 = As[bloc][4] + T[4 * 6 + j];
            float v5 = As[bloc][5] + T[5 * 6 + j];
            float mx = fmaxf(fmaxf(fmaxf(v0, v1), fmaxf(v2, v3)), fmaxf(v4, v5));
            float ssum = expf(v0 - mx) + expf(v1 - mx) + expf(v2 - mx)
                       + expf(v3 - mx) + expf(v4 - mx) + expf(v5 - mx);
            float na = mx + logf(ssum) + e;
            float m = mask[b * 128 + l];
            a = m * na + (1.f - m) * a;
            As[bloc][j] = a;
        }
        if (j == 0) {
            float v0 = As[bloc][0], v1 = As[bloc][1], v2 = As[bloc][2];
            float v3 = As[bloc][3], v4 = As[bloc][4], v5 = As[bloc][5];
            float mx = fmaxf(fmaxf(fmaxf(v0, v1), fmaxf(v2, v3)), fmaxf(v4, v5));
            float ssum = expf(v0 - mx) + expf(v1 - mx) + expf(v2 - mx)
                       + expf(v3 - mx) + expf(v4 - mx) + expf(v5 - mx);
            float logZ = mx + logf(ssum);
            float scb = red[bloc * 6 + 0] + red[bloc * 6 + 1] + red[bloc * 6 + 2]
                      + red[bloc * 6 + 3] + red[bloc * 6 + 4] + red[bloc * 6 + 5];
            res[bloc] = logZ - scb;
        }
        if (tid == 0) {
            float tot = res[0] + res[1] + res[2] + res[3]
                      + res[4] + res[5] + res[6] + res[7];
            atomicAdd(outp, tot * (1.f / 32.f));
        }
    }
}

// ---------------------------------------------------------------------------
extern "C" void kernel_launch(void* const* d_in, const int* in_sizes, int n_in,
                              void* d_out, int out_size, void* d_ws, size_t ws_size,
                              hipStream_t stream)
{
    const int*   iv    = (const int*)d_in[0];
    const int*   ov    = (const int*)d_in[1];
    const int*   ch    = (const int*)d_in[2];
    const int*   tgt   = (const int*)d_in[3];
    const float* mask  = (const float*)d_in[4];
    const float* emb   = (const float*)d_in[5];
    const float* ooevT = (const float*)d_in[6];
    const float* ctab  = (const float*)d_in[7];
    const float* convW = (const float*)d_in[8];
    const float* convB = (const float*)d_in[9];
    const float* wih0  = (const float*)d_in[10];
    const float* whh0  = (const float*)d_in[11];
    const float* b0    = (const float*)d_in[12];
    const float* wih1  = (const float*)d_in[13];
    const float* whh1  = (const float*)d_in[14];
    const float* b1    = (const float*)d_in[15];
    const float* crfW  = (const float*)d_in[16];
    const float* crfB  = (const float*)d_in[17];
    const float* crfT  = (const float*)d_in[18];
    float* outp = (float*)d_out;

    char* ws = (char*)d_ws;
    size_t off = 0;
    auto alloc = [&](size_t bytes) {
        void* p = ws + off;
        off = (off + bytes + 255) & ~(size_t)255;
        return p;
    };
    unsigned short* inp_bf = (unsigned short*)alloc((size_t)4096 * 512 * 2);
    float* xs     = (float*)alloc((size_t)4096 * 2048 * 4);
    float* out0   = (float*)alloc((size_t)4096 * 512 * 4);
    float* out1   = (float*)alloc((size_t)4096 * 512 * 4);
    unsigned short* outb0 = (unsigned short*)alloc((size_t)4096 * 512 * 2);
    unsigned short* outb1 = (unsigned short*)alloc((size_t)4096 * 512 * 2);
    float* em     = (float*)alloc((size_t)4096 * 48 * 4);
    uint4* Wp0    = (uint4*)alloc((size_t)2 * 64 * 256 * 16);
    uint4* Wp1    = (uint4*)alloc((size_t)2 * 64 * 256 * 16);
    unsigned short* wbf0 = (unsigned short*)alloc((size_t)2048 * 512 * 2);
    unsigned short* wbf1 = (unsigned short*)alloc((size_t)2048 * 512 * 2);
    unsigned short* crfbf = (unsigned short*)alloc((size_t)128 * 512 * 2);
    float* convWT = (float*)alloc((size_t)30000 * 4);

    prep_all<<<MISC_BLOCKS + 64, 256, 0, stream>>>(
        wih0, wih1, crfW, convW, whh0, whh1,
        wbf0, wbf1, crfbf, convWT, Wp0, Wp1, outp);
    embed_conv<<<4096, 512, 0, stream>>>(iv, ov, ch, emb, ooevT, ctab, convWT, convB, inp_bf);
    gemm_bf16<<<dim3(16, 32), 256, 0, stream>>>(inp_bf, wbf0, b0, xs, 2048, 2048);
    lstm_rec<<<64, 1024, 0, stream>>>(xs, Wp0, mask, out0, outb0);
    gemm_bf16<<<dim3(16, 32), 256, 0, stream>>>(outb0, wbf1, b1, xs, 2048, 2048);
    lstm_rec<<<64, 1024, 0, stream>>>(xs, Wp1, mask, out1, outb1);
    gemm_bf16<<<dim3(1, 32), 256, 0, stream>>>(outb1, crfbf, crfB, em, 48, 48);
    crf_loss<<<32, 64, 0, stream>>>(em, crfT, tgt, mask, outp);
}

// Round 6
// 1191.142 us; speedup vs baseline: 1.0029x; 1.0029x over previous
//
#include <hip/hip_runtime.h>
#include <hip/hip_bf16.h>

// Problem constants
// B=32, L=128, C=20, TOKEN_EMBED=300, CHAR_EMBED=50, NUM_FILTERS=200, KERNEL=3
// HID=256, LABELS=8, NS=6, D0=500 (padded 512), D1=512, BL=4096

typedef float floatx2 __attribute__((ext_vector_type(2)));
typedef short bf16x8 __attribute__((ext_vector_type(8)));
typedef float f32x4  __attribute__((ext_vector_type(4)));

__device__ __forceinline__ unsigned short f2bf(float x) {
    unsigned u = __float_as_uint(x);
    unsigned r = (u + 0x7fffu + ((u >> 16) & 1u)) >> 16;
    return (unsigned short)r;
}

// packed fp32 FMA with op_sel broadcast of h (low or high half of the pair)
__device__ __forceinline__ void pk_fma_bl(floatx2& acc, floatx2 w, floatx2 h) {
    asm("v_pk_fma_f32 %0, %1, %2, %0 op_sel_hi:[1,0,1]" : "+v"(acc) : "v"(w), "v"(h));
}
__device__ __forceinline__ void pk_fma_bh(floatx2& acc, floatx2 w, floatx2 h) {
    asm("v_pk_fma_f32 %0, %1, %2, %0 op_sel:[0,1,0]" : "+v"(acc) : "v"(w), "v"(h));
}

__device__ __forceinline__ float fsig(float x) {
    return __builtin_amdgcn_rcpf(1.f + __expf(-x));
}
__device__ __forceinline__ float ftanh(float x) {
    return fmaf(-2.f, __builtin_amdgcn_rcpf(1.f + __expf(2.f * x)), 1.f);
}

// LDS-only barrier: order hs/part (lgkmcnt) but do NOT drain vmcnt —
// outb stores and streamed weight loads stay in flight across steps.
// (__syncthreads would emit s_waitcnt vmcnt(0) before s_barrier.)
#define BAR_LDS() asm volatile("s_waitcnt lgkmcnt(0)\n\ts_barrier" ::: "memory")

// 4 k-values (one uint4 of packed fp8 gate weights) x 4 gates = 16 MACs
__device__ __forceinline__ void dot4(floatx2& aif0, floatx2& ago0,
                                     floatx2& aif1, floatx2& ago1,
                                     uint4 w, const float* hsp, int k4) {
    float4 hv = *(const float4*)(hsp + k4 * 4);   // broadcast (same addr all lanes)
    floatx2 h01; h01.x = hv.x; h01.y = hv.y;
    floatx2 h23; h23.x = hv.z; h23.y = hv.w;
    floatx2 lo, hi;
    lo = __builtin_amdgcn_cvt_pk_f32_fp8((int)w.x, false);
    hi = __builtin_amdgcn_cvt_pk_f32_fp8((int)w.x, true);
    pk_fma_bl(aif0, lo, h01); pk_fma_bl(ago0, hi, h01);
    lo = __builtin_amdgcn_cvt_pk_f32_fp8((int)w.y, false);
    hi = __builtin_amdgcn_cvt_pk_f32_fp8((int)w.y, true);
    pk_fma_bh(aif0, lo, h01); pk_fma_bh(ago0, hi, h01);
    lo = __builtin_amdgcn_cvt_pk_f32_fp8((int)w.z, false);
    hi = __builtin_amdgcn_cvt_pk_f32_fp8((int)w.z, true);
    pk_fma_bl(aif1, lo, h23); pk_fma_bl(ago1, hi, h23);
    lo = __builtin_amdgcn_cvt_pk_f32_fp8((int)w.w, false);
    hi = __builtin_amdgcn_cvt_pk_f32_fp8((int)w.w, true);
    pk_fma_bh(aif1, lo, h23); pk_fma_bh(ago1, hi, h23);
}

// ---------------------------------------------------------------------------
// prep_all: merged prep.
//  blocks [0, 8566): elementwise misc (coalesced):
//   - wih0 (2048x500 fp32) -> wbf0 (2048x512 bf16, zero-padded)
//   - wih1 (2048x512 fp32) -> wbf1 (2048x512 bf16)
//   - crf_w -> crfbf (128x512 bf16, rows 48..127 zero)  [row jj = kL*6+n]
//   - conv_w transpose -> convWT ; outp zero
//  blocks [8566, 8630): w_hh tile-transpose pack -> fp8 uint4 per (dir,k4,t)
// ---------------------------------------------------------------------------
#define MISC_BLOCKS 8566
__global__ __launch_bounds__(256) void prep_all(
    const float* __restrict__ wih0, const float* __restrict__ wih1,
    const float* __restrict__ crf_w, const float* __restrict__ conv_w,
    const float* __restrict__ wh0, const float* __restrict__ wh1,
    unsigned short* __restrict__ wbf0, unsigned short* __restrict__ wbf1,
    unsigned short* __restrict__ crfbf, float* __restrict__ convWT,
    uint4* __restrict__ Wp0, uint4* __restrict__ Wp1,
    float* __restrict__ outp)
{
    __shared__ float sxw[4][64][65];
    const int tid = threadIdx.x;
    if (blockIdx.x >= MISC_BLOCKS) {
        const int bid   = blockIdx.x - MISC_BLOCKS;
        const int layer = bid >> 5;
        const int dir   = (bid >> 4) & 1;
        const int tt    = (bid >> 2) & 3;
        const int ktile = bid & 3;
        const float* w = (layer ? wh1 : wh0) + dir * 1024 * 256;
        uint4* dst = layer ? Wp1 : Wp0;
        const int t0 = tt * 64, k0 = ktile * 64;
        #pragma unroll
        for (int g = 0; g < 4; ++g)
            #pragma unroll
            for (int q = 0; q < 4; ++q) {
                int lin = q * 256 + tid;
                int tr = lin >> 4, kc = (lin & 15) * 4;
                float4 v = *(const float4*)&w[(g * 256 + t0 + tr) * 256 + k0 + kc];
                sxw[g][tr][kc + 0] = v.x; sxw[g][tr][kc + 1] = v.y;
                sxw[g][tr][kc + 2] = v.z; sxw[g][tr][kc + 3] = v.w;
            }
        __syncthreads();
        const int t = tid & 63, k4g = tid >> 6;
        #pragma unroll
        for (int q = 0; q < 4; ++q) {
            int k4l = k4g * 4 + q;           // 0..15
            unsigned wrd[4];
            #pragma unroll
            for (int j = 0; j < 4; ++j) {
                int kc = k4l * 4 + j;
                float wi = sxw[0][t][kc], wf = sxw[1][t][kc];
                float wg = sxw[2][t][kc], wo = sxw[3][t][kc];
                int u = __builtin_amdgcn_cvt_pk_fp8_f32(wi, wf, 0, false);
                u     = __builtin_amdgcn_cvt_pk_fp8_f32(wg, wo, u, true);
                wrd[j] = (unsigned)u;
            }
            int k4 = (k0 >> 2) + k4l;
            dst[((size_t)dir * 64 + k4) * 256 + (t0 + t)] =
                make_uint4(wrd[0], wrd[1], wrd[2], wrd[3]);
        }
        return;
    }
    int idx = blockIdx.x * 256 + tid;
    if (idx == 0) outp[0] = 0.f;
    const int NW = 2048 * 512;
    if (idx < NW) {
        int n = idx >> 9, k = idx & 511;
        wbf0[idx] = (k < 500) ? f2bf(wih0[n * 500 + k]) : (unsigned short)0;
        return;
    }
    idx -= NW;
    if (idx < NW) {
        wbf1[idx] = f2bf(wih1[idx]);
        return;
    }
    idx -= NW;
    if (idx < 128 * 512) {
        int jj = idx >> 9, d = idx & 511;
        unsigned short v = 0;
        if (jj < 48) {
            int kL = jj / 6, n = jj % 6;
            v = f2bf(crf_w[(kL * 512 + d) * 6 + n]);
        }
        crfbf[idx] = v;
        return;
    }
    idx -= 128 * 512;
    if (idx < 30000) {
        int f = idx % 200, ek = idx / 200;
        int e = ek / 3, kk = ek % 3;
        convWT[idx] = conv_w[(f * 50 + e) * 3 + kk];
        return;
    }
}

// ---------------------------------------------------------------------------
// Embeddings + char conv + concat -> inp (4096 x 512 bf16, cols 500..511 = 0)
// 512 threads: conv e-loop split in half (eh=tid>>8), partials combined in LDS.
// ---------------------------------------------------------------------------
__global__ __launch_bounds__(512) void embed_conv(
    const int* __restrict__ iv, const int* __restrict__ ov, const int* __restrict__ ch,
    const float* __restrict__ emb, const float* __restrict__ ooev, const float* __restrict__ ctab,
    const float* __restrict__ convWT, const float* __restrict__ convB,
    unsigned short* __restrict__ inp)
{
    const int bl = blockIdx.x;
    const int tid = threadIdx.x;
    __shared__ float sx[50 * 20];
    __shared__ float pc[200][22];
    const int ivv = iv[bl];
    const int ovv = ov[bl];
    const float mo = (ovv != 0) ? 1.f : 0.f;
    if (tid < 300)
        inp[bl * 512 + tid] = f2bf(emb[(size_t)ivv * 300 + tid] + mo * ooev[(size_t)ovv * 300 + tid]);
    if (tid >= 500) inp[bl * 512 + tid] = 0;    // pad cols 500..511
    for (int i = tid; i < 1000; i += 512) {
        int cI = i / 50, e = i % 50;
        int id = ch[bl * 20 + cI];
        sx[e * 20 + cI] = id ? ctab[id * 50 + e] : 0.f;
    }
    __syncthreads();
    const int f = tid & 255, eh = tid >> 8;
    float acc[22];
    if (f < 200) {
        float init = eh ? 0.f : convB[f];
        #pragma unroll
        for (int o = 0; o < 22; ++o) acc[o] = init;
        const int e0 = eh * 25;
        for (int e = e0; e < e0 + 25; ++e) {
            float xr[20];
            #pragma unroll
            for (int q = 0; q < 5; ++q) {
                float4 v = *(const float4*)&sx[e * 20 + q * 4];
                xr[q * 4 + 0] = v.x; xr[q * 4 + 1] = v.y;
                xr[q * 4 + 2] = v.z; xr[q * 4 + 3] = v.w;
            }
            float w0 = convWT[(e * 3 + 0) * 200 + f];
            float w1 = convWT[(e * 3 + 1) * 200 + f];
            float w2 = convWT[(e * 3 + 2) * 200 + f];
            #pragma unroll
            for (int o = 0; o < 22; ++o) {
                float s = acc[o];
                if (o >= 2)            s = fmaf(xr[o - 2], w0, s);
                if (o >= 1 && o <= 20) s = fmaf(xr[o - 1], w1, s);
                if (o <= 19)           s = fmaf(xr[o],     w2, s);
                acc[o] = s;
            }
        }
        if (eh) {
            #pragma unroll
            for (int o = 0; o < 22; ++o) pc[f][o] = acc[o];
        }
    }
    __syncthreads();
    if (f < 200 && eh == 0) {
        float mx = acc[0] + pc[f][0];
        #pragma unroll
        for (int o = 1; o < 22; ++o) mx = fmaxf(mx, acc[o] + pc[f][o]);
        inp[bl * 512 + 300 + f] = f2bf(1.f / (1.f + expf(-mx)));
    }
}

// ---------------------------------------------------------------------------
// Pure-bf16 MFMA GEMM: A (Mx512 bf16), B (rows of 512 bf16 = output cols),
// K=512 exact. ldC = C row stride; Nguard = #valid output cols.
// ---------------------------------------------------------------------------
__global__ __launch_bounds__(256) void gemm_bf16(
    const unsigned short* __restrict__ A, const unsigned short* __restrict__ Bm,
    const float* __restrict__ bias, float* __restrict__ C, int ldC, int Nguard)
{
    __shared__ unsigned short As[4][128][8];
    __shared__ unsigned short Bs[4][128][8];
    const int tid  = threadIdx.x;
    const int wave = tid >> 6, lane = tid & 63;
    const int quad = lane >> 4, lr = lane & 15;
    const int m0 = blockIdx.y * 128, n0 = blockIdx.x * 128;

    f32x4 acc[2][8];
    #pragma unroll
    for (int mt = 0; mt < 2; ++mt)
        #pragma unroll
        for (int nt = 0; nt < 8; ++nt) acc[mt][nt] = (f32x4){0.f, 0.f, 0.f, 0.f};

    for (int kt = 0; kt < 16; ++kt) {
        #pragma unroll
        for (int p = 0; p < 2; ++p) {
            int lin = p * 256 + tid;
            int row = lin & 127, c = lin >> 7;     // c in 0..3 over both passes
            *(bf16x8*)&As[c][row][0] =
                *(const bf16x8*)&A[(size_t)(m0 + row) * 512 + kt * 32 + c * 8];
            *(bf16x8*)&Bs[c][row][0] =
                *(const bf16x8*)&Bm[(size_t)(n0 + row) * 512 + kt * 32 + c * 8];
        }
        __syncthreads();
        bf16x8 bfr[8];
        #pragma unroll
        for (int nt = 0; nt < 8; ++nt)
            bfr[nt] = *(const bf16x8*)&Bs[quad][nt * 16 + lr][0];
        #pragma unroll
        for (int mt = 0; mt < 2; ++mt) {
            bf16x8 afr = *(const bf16x8*)&As[quad][wave * 32 + mt * 16 + lr][0];
            #pragma unroll
            for (int nt = 0; nt < 8; ++nt)
                acc[mt][nt] = __builtin_amdgcn_mfma_f32_16x16x32_bf16(
                    afr, bfr[nt], acc[mt][nt], 0, 0, 0);
        }
        __syncthreads();
    }
    #pragma unroll
    for (int mt = 0; mt < 2; ++mt)
        #pragma unroll
        for (int r = 0; r < 4; ++r) {
            int m = m0 + wave * 32 + mt * 16 + quad * 4 + r;
            #pragma unroll
            for (int nt = 0; nt < 8; ++nt) {
                int n = n0 + nt * 16 + lr;
                if (n < Nguard) C[(size_t)m * ldC + n] = acc[mt][nt][r] + bias[n];
            }
        }
}

// ---------------------------------------------------------------------------
// LSTM recurrence v14: v13b structure (1024 threads, 4-way k-split, 36 LDS
// groups + 28 L2-streamed groups) with two changes:
//  (a) dead fp32 `out` store removed (nothing consumed it since R4) -> only
//      the bf16 outb store remains (half the store traffic);
//  (b) in-loop __syncthreads() -> BAR_LDS() (s_waitcnt lgkmcnt(0); s_barrier):
//      hs/part LDS ordering preserved, but the per-step vmcnt(0) drain that
//      __syncthreads emits is gone -- outb stores and streamed weight loads
//      stay in flight across barriers.
// ---------------------------------------------------------------------------
#define L4LDS 36
__global__ __launch_bounds__(1024) void lstm_rec(
    const float* __restrict__ xs, const uint4* __restrict__ Wp,
    const float* __restrict__ mask, unsigned short* __restrict__ outb)
{
    const int tid = threadIdx.x;
    const int t   = tid & 255;
    const int kh  = tid >> 8;            // wave-uniform
    const int b   = blockIdx.x >> 1;
    const int dir = blockIdx.x & 1;
    __shared__ uint4 wlds[L4LDS * 256];          // 147456 B
    __shared__ float4 part[3 * 256];             // 12288 B
    __shared__ __align__(16) float hs[256];
    __shared__ float msk[128];

    const uint4* wp = Wp + (size_t)dir * 64 * 256;
    for (int j = tid; j < L4LDS * 256; j += 1024) wlds[j] = wp[j];
    if (tid < 256) hs[tid] = 0.f;
    if (tid < 128) msk[tid] = mask[b * 128 + tid];
    __syncthreads();

    const uint4* sp = wp + t;                    // streamed: sp[g*256]
    float h = 0.f, c = 0.f;                      // live on kh==0 (t-owners)
    for (int s = 0; s < 128; ++s) {
        const int l = dir ? (127 - s) : s;
        floatx2 aif0 = {0.f, 0.f}, ago0 = {0.f, 0.f};
        floatx2 aif1 = {0.f, 0.f}, ago1 = {0.f, 0.f};
        float gi, gf, gg2, go;
        if (kh == 0) {
            const float* gxp = xs + ((size_t)(b * 128 + l) * 2048 + dir * 1024 + t);
            gi = gxp[0]; gf = gxp[256]; gg2 = gxp[512]; go = gxp[768];
            #pragma unroll 4
            for (int k4 = 0; k4 < 13; ++k4)
                dot4(aif0, ago0, aif1, ago1, wlds[k4 * 256 + t], hs, k4);
        } else if (kh == 1) {
            uint4 a0 = sp[36 * 256], a1 = sp[37 * 256];
            uint4 a2 = sp[38 * 256], a3 = sp[39 * 256];
            #pragma unroll 4
            for (int k4 = 13; k4 < 27; ++k4)
                dot4(aif0, ago0, aif1, ago1, wlds[k4 * 256 + t], hs, k4);
            dot4(aif0, ago0, aif1, ago1, a0, hs, 36);
            dot4(aif0, ago0, aif1, ago1, a1, hs, 37);
            dot4(aif0, ago0, aif1, ago1, a2, hs, 38);
            dot4(aif0, ago0, aif1, ago1, a3, hs, 39);
        } else if (kh == 2) {
            uint4 a0 = sp[40 * 256], a1 = sp[41 * 256];
            uint4 a2 = sp[42 * 256], a3 = sp[43 * 256];
            uint4 b0 = sp[44 * 256], b1 = sp[45 * 256];
            uint4 b2 = sp[46 * 256], b3 = sp[47 * 256];
            #pragma unroll 3
            for (int k4 = 27; k4 < 36; ++k4)
                dot4(aif0, ago0, aif1, ago1, wlds[k4 * 256 + t], hs, k4);
            dot4(aif0, ago0, aif1, ago1, a0, hs, 40);
            dot4(aif0, ago0, aif1, ago1, a1, hs, 41);
            dot4(aif0, ago0, aif1, ago1, a2, hs, 42);
            dot4(aif0, ago0, aif1, ago1, a3, hs, 43);
            dot4(aif0, ago0, aif1, ago1, b0, hs, 44);
            dot4(aif0, ago0, aif1, ago1, b1, hs, 45);
            dot4(aif0, ago0, aif1, ago1, b2, hs, 46);
            dot4(aif0, ago0, aif1, ago1, b3, hs, 47);
        } else {
            uint4 a0 = sp[48 * 256], a1 = sp[49 * 256];
            uint4 a2 = sp[50 * 256], a3 = sp[51 * 256];
            uint4 b0 = sp[52 * 256], b1 = sp[53 * 256];
            uint4 b2 = sp[54 * 256], b3 = sp[55 * 256];
            dot4(aif0, ago0, aif1, ago1, a0, hs, 48);
            dot4(aif0, ago0, aif1, ago1, a1, hs, 49);
            dot4(aif0, ago0, aif1, ago1, a2, hs, 50);
            dot4(aif0, ago0, aif1, ago1, a3, hs, 51);
            a0 = sp[56 * 256]; a1 = sp[57 * 256];
            a2 = sp[58 * 256]; a3 = sp[59 * 256];
            dot4(aif0, ago0, aif1, ago1, b0, hs, 52);
            dot4(aif0, ago0, aif1, ago1, b1, hs, 53);
            dot4(aif0, ago0, aif1, ago1, b2, hs, 54);
            dot4(aif0, ago0, aif1, ago1, b3, hs, 55);
            b0 = sp[60 * 256]; b1 = sp[61 * 256];
            b2 = sp[62 * 256]; b3 = sp[63 * 256];
            dot4(aif0, ago0, aif1, ago1, a0, hs, 56);
            dot4(aif0, ago0, aif1, ago1, a1, hs, 57);
            dot4(aif0, ago0, aif1, ago1, a2, hs, 58);
            dot4(aif0, ago0, aif1, ago1, a3, hs, 59);
            dot4(aif0, ago0, aif1, ago1, b0, hs, 60);
            dot4(aif0, ago0, aif1, ago1, b1, hs, 61);
            dot4(aif0, ago0, aif1, ago1, b2, hs, 62);
            dot4(aif0, ago0, aif1, ago1, b3, hs, 63);
        }
        floatx2 aif = aif0 + aif1;
        floatx2 ago = ago0 + ago1;
        if (kh != 0)
            part[(kh - 1) * 256 + t] = make_float4(aif.x, aif.y, ago.x, ago.y);
        BAR_LDS();                       // partials visible; hs reads done
        if (kh == 0) {
            float4 p0 = part[t], p1 = part[256 + t], p2 = part[512 + t];
            float sai = aif.x + gi  + p0.x + p1.x + p2.x;
            float saf = aif.y + gf  + p0.y + p1.y + p2.y;
            float sag = ago.x + gg2 + p0.z + p1.z + p2.z;
            float sao = ago.y + go  + p0.w + p1.w + p2.w;
            float ig = fsig(sai);
            float fg = fsig(saf);
            float og = fsig(sao);
            float gg = ftanh(sag);
            float cn = fmaf(fg, c, ig * gg);
            float hn = og * ftanh(cn);
            float m = msk[l];
            h = m * hn + (1.f - m) * h;
            c = m * cn + (1.f - m) * c;
            hs[t] = h;
            outb[(size_t)(b * 128 + l) * 512 + dir * 256 + t] = f2bf(h);
        }
        BAR_LDS();                       // new hs visible for next step
    }
}
#undef L4LDS

// ---------------------------------------------------------------------------
// CRF loss v2: 32 blocks = (label k x batch-quarter), 64 threads (1 wave,
// 48 active = 8 batches x 6 states). Single-wave lockstep -> no barriers.
// ---------------------------------------------------------------------------
__global__ __launch_bounds__(64) void crf_loss(
    const float* __restrict__ em, const float* __restrict__ trans,
    const int* __restrict__ target, const float* __restrict__ mask,
    float* __restrict__ outp)
{
    const int k  = blockIdx.x >> 2;
    const int bq = blockIdx.x & 3;
    const int tid = threadIdx.x;
    __shared__ float T[36];
    __shared__ float As[8][6];
    __shared__ float red[48];
    __shared__ float res[8];
    if (tid < 36) T[tid] = trans[k * 36 + tid];
    if (tid < 48) {
        const int bloc = tid / 6;
        const int j    = tid - bloc * 6;
        const int b    = bq * 8 + bloc;
        const int* tg = target + (k * 32 + b) * 128;
        float sc = 0.f;
        for (int l = j; l < 128; l += 6) {
            int y = tg[l];
            float m = mask[b * 128 + l];
            sc += m * em[(b * 128 + l) * 48 + k * 6 + y];
            if (l > 0) sc += m * T[tg[l - 1] * 6 + y];
        }
        red[tid] = sc;
        float a = em[(b * 128) * 48 + k * 6 + j];
        As[bloc][j] = a;
        for (int l = 1; l < 128; ++l) {
            float e = em[(b * 128 + l) * 48 + k * 6 + j];
            float v0 = As[bloc][0] + T[0 * 6 + j];
            float v1 = As[bloc][1] + T[1 * 6 + j];
            float v2 = As[bloc][2] + T[2 * 6 + j];
            float v3 = As[bloc][3] + T[3 * 6 + j];
            float v4 = As[bloc][4] + T[4 * 6 + j];
            float v5 = As[bloc][5] + T[5 * 6 + j];
            float mx = fmaxf(fmaxf(fmaxf(v0, v1), fmaxf(v2, v3)), fmaxf(v4, v5));
            float ssum = expf(v0 - mx) + expf(v1 - mx) + expf(v2 - mx)
                       + expf(v3 - mx) + expf(v4 - mx) + expf(v5 - mx);
            float na = mx + logf(ssum) + e;
            float m = mask[b * 128 + l];
            a = m * na + (1.f - m) * a;
            As[bloc][j] = a;
        }
        if (j == 0) {
            float v0 = As[bloc][0], v1 = As[bloc][1], v2 = As[bloc][2];
            float v3 = As[bloc][3], v4 = As[bloc][4], v5 = As[bloc][5];
            float mx = fmaxf(fmaxf(fmaxf(v0, v1), fmaxf(v2, v3)), fmaxf(v4, v5));
            float ssum = expf(v0 - mx) + expf(v1 - mx) + expf(v2 - mx)
                       + expf(v3 - mx) + expf(v4 - mx) + expf(v5 - mx);
            float logZ = mx + logf(ssum);
            float scb = red[bloc * 6 + 0] + red[bloc * 6 + 1] + red[bloc * 6 + 2]
                      + red[bloc * 6 + 3] + red[bloc * 6 + 4] + red[bloc * 6 + 5];
            res[bloc] = logZ - scb;
        }
        if (tid == 0) {
            float tot = res[0] + res[1] + res[2] + res[3]
                      + res[4] + res[5] + res[6] + res[7];
            atomicAdd(outp, tot * (1.f / 32.f));
        }
    }
}

// ---------------------------------------------------------------------------
extern "C" void kernel_launch(void* const* d_in, const int* in_sizes, int n_in,
                              void* d_out, int out_size, void* d_ws, size_t ws_size,
                              hipStream_t stream)
{
    const int*   iv    = (const int*)d_in[0];
    const int*   ov    = (const int*)d_in[1];
    const int*   ch    = (const int*)d_in[2];
    const int*   tgt   = (const int*)d_in[3];
    const float* mask  = (const float*)d_in[4];
    const float* emb   = (const float*)d_in[5];
    const float* ooevT = (const float*)d_in[6];
    const float* ctab  = (const float*)d_in[7];
    const float* convW = (const float*)d_in[8];
    const float* convB = (const float*)d_in[9];
    const float* wih0  = (const float*)d_in[10];
    const float* whh0  = (const float*)d_in[11];
    const float* b0    = (const float*)d_in[12];
    const float* wih1  = (const float*)d_in[13];
    const float* whh1  = (const float*)d_in[14];
    const float* b1    = (const float*)d_in[15];
    const float* crfW  = (const float*)d_in[16];
    const float* crfB  = (const float*)d_in[17];
    const float* crfT  = (const float*)d_in[18];
    float* outp = (float*)d_out;

    char* ws = (char*)d_ws;
    size_t off = 0;
    auto alloc = [&](size_t bytes) {
        void* p = ws + off;
        off = (off + bytes + 255) & ~(size_t)255;
        return p;
    };
    unsigned short* inp_bf = (unsigned short*)alloc((size_t)4096 * 512 * 2);
    float* xs     = (float*)alloc((size_t)4096 * 2048 * 4);
    unsigned short* outb0 = (unsigned short*)alloc((size_t)4096 * 512 * 2);
    unsigned short* outb1 = (unsigned short*)alloc((size_t)4096 * 512 * 2);
    float* em     = (float*)alloc((size_t)4096 * 48 * 4);
    uint4* Wp0    = (uint4*)alloc((size_t)2 * 64 * 256 * 16);
    uint4* Wp1    = (uint4*)alloc((size_t)2 * 64 * 256 * 16);
    unsigned short* wbf0 = (unsigned short*)alloc((size_t)2048 * 512 * 2);
    unsigned short* wbf1 = (unsigned short*)alloc((size_t)2048 * 512 * 2);
    unsigned short* crfbf = (unsigned short*)alloc((size_t)128 * 512 * 2);
    float* convWT = (float*)alloc((size_t)30000 * 4);

    prep_all<<<MISC_BLOCKS + 64, 256, 0, stream>>>(
        wih0, wih1, crfW, convW, whh0, whh1,
        wbf0, wbf1, crfbf, convWT, Wp0, Wp1, outp);
    embed_conv<<<4096, 512, 0, stream>>>(iv, ov, ch, emb, ooevT, ctab, convWT, convB, inp_bf);
    gemm_bf16<<<dim3(16, 32), 256, 0, stream>>>(inp_bf, wbf0, b0, xs, 2048, 2048);
    lstm_rec<<<64, 1024, 0, stream>>>(xs, Wp0, mask, outb0);
    gemm_bf16<<<dim3(16, 32), 256, 0, stream>>>(outb0, wbf1, b1, xs, 2048, 2048);
    lstm_rec<<<64, 1024, 0, stream>>>(xs, Wp1, mask, outb1);
    gemm_bf16<<<dim3(1, 32), 256, 0, stream>>>(outb1, crfbf, crfB, em, 48, 48);
    crf_loss<<<32, 64, 0, stream>>>(em, crfT, tgt, mask, outp);
}